// Round 4
// baseline (222.407 us; speedup 1.0000x reference)
//
#include <hip/hip_runtime.h>
#include <hip/hip_bf16.h>
#include <stdint.h>

// MHA fwd, B=4 T=2048 D=768 H=12 HD=64, fp32 io, NO mask, scale=1/8.
// R4: attn on mfma_32x32x16 with K-row permutation so S^T regs == PV A-frag
// (P never touches LDS); wave=64 q-rows sharing K/V frags -> 16KB LDS / 32 MFMA-32
// per wave-iter. qkv Q/K epilogue via LDS -> coalesced b128 stores.

#define HH   12
#define TT   2048
#define DIN  768
#define DOUT 768
#define HD   64
#define BB   4
#define MTOT (BB*TT)      // 8192
#define NQKV (3*DOUT)     // 2304
#define QSCALE 0.1803368801111832f   // 0.125 * log2(e)

typedef float  float4v  __attribute__((ext_vector_type(4)));
typedef float  float16v __attribute__((ext_vector_type(16)));
typedef __bf16 bf16x8   __attribute__((ext_vector_type(8)));
typedef short  short8v  __attribute__((ext_vector_type(8)));

#define AS1 __attribute__((address_space(1)))
#define AS3 __attribute__((address_space(3)))

static __device__ __forceinline__ void gload_lds16(const void* g, void* l) {
    __builtin_amdgcn_global_load_lds((AS1 void*)g, (AS3 void*)l, 16, 0, 0);
}

static __device__ __forceinline__ short f2bf(float f) {
    __bf16 h = (__bf16)f;
    return __builtin_bit_cast(short, h);
}

__global__ __launch_bounds__(256) void cast_x_kernel(const float* __restrict__ x,
                                                     short* __restrict__ xb, int n4) {
    int i = blockIdx.x * 256 + threadIdx.x;
    if (i >= n4) return;
    float4 v = ((const float4*)x)[i];
    short4 o;
    o.x = f2bf(v.x); o.y = f2bf(v.y); o.z = f2bf(v.z); o.w = f2bf(v.w);
    ((short4*)xb)[i] = o;
}

// Tiled transpose: Wqkvt[n][k] = W*[k][n] (bf16), Wot[n][k] = Wo[k][n].
__global__ __launch_bounds__(256) void prep_w_kernel(const float* __restrict__ Wq,
                                                     const float* __restrict__ Wk,
                                                     const float* __restrict__ Wv,
                                                     const float* __restrict__ Wo,
                                                     short* __restrict__ Wqkvt,
                                                     short* __restrict__ Wot) {
    __shared__ short tile[32 * 33];
    const int bx = blockIdx.x, by = blockIdx.y, bz = blockIdx.z;
    const float* W = (bz == 0) ? Wq : (bz == 1) ? Wk : (bz == 2) ? Wv : Wo;
    const int tx = threadIdx.x & 31, ty = threadIdx.x >> 5;
    for (int i = 0; i < 4; i++) {
        int k = by * 32 + ty + i * 8;
        tile[(ty + i * 8) * 33 + tx] = f2bf(W[(size_t)k * DOUT + bx * 32 + tx]);
    }
    __syncthreads();
    for (int i = 0; i < 4; i++) {
        int n = bx * 32 + ty + i * 8;
        int k = by * 32 + tx;
        short v = tile[tx * 33 + ty + i * 8];
        if (bz < 3) Wqkvt[(size_t)(bz * DOUT + n) * DIN + k] = v;
        else        Wot[(size_t)n * DOUT + k] = v;
    }
}

// ---- QKV GEMM: C[8192][2304] = Xb @ Wqkvt^T ----
__global__ __launch_bounds__(256) void qkv_gemm_kernel(const short* __restrict__ Xb,
                                                       const short* __restrict__ Wt,
                                                       short* __restrict__ Qb,
                                                       short* __restrict__ Kb,
                                                       short* __restrict__ Vt) {
    __shared__ __align__(16) short lds[8192];    // ldsA | ldsB; reused as epilogue tile
    short* ldsA = lds;
    short* ldsB = lds + 4096;
    const int t = threadIdx.x;
    const int w = t >> 6, lane = t & 63;
    const int quad = lane >> 4, l15 = lane & 15;
    const int m0 = blockIdx.x * 128, n0 = blockIdx.y * 128;
    const int wm = (w >> 1) * 64, wn = (w & 1) * 64;

    float4v acc[4][4];
    for (int i = 0; i < 4; i++)
        for (int j = 0; j < 4; j++)
            acc[i][j] = (float4v)0.0f;

    const int rA = t >> 2;
    const int cSw = ((t & 3) ^ ((t >> 3) & 3)) * 8;
    const short* gA0 = Xb + (size_t)(m0 + rA) * DIN + cSw;
    const short* gB0 = Wt + (size_t)(n0 + rA) * DIN + cSw;
    const int pos = (quad ^ ((l15 >> 1) & 3)) * 8;

    for (int k0 = 0; k0 < DIN; k0 += 32) {
        gload_lds16(gA0 + k0,            &ldsA[t * 8]);
        gload_lds16(gA0 + 64 * DIN + k0, &ldsA[(t + 256) * 8]);
        gload_lds16(gB0 + k0,            &ldsB[t * 8]);
        gload_lds16(gB0 + 64 * DIN + k0, &ldsB[(t + 256) * 8]);
        __syncthreads();
        bf16x8 af[4], bfr[4];
        for (int i = 0; i < 4; i++) af[i]  = *(const bf16x8*)&ldsA[(wm + i * 16 + l15) * 32 + pos];
        for (int j = 0; j < 4; j++) bfr[j] = *(const bf16x8*)&ldsB[(wn + j * 16 + l15) * 32 + pos];
        for (int i = 0; i < 4; i++)
            for (int j = 0; j < 4; j++)
                acc[i][j] = __builtin_amdgcn_mfma_f32_16x16x32_bf16(af[i], bfr[j], acc[i][j], 0, 0, 0);
        __syncthreads();
    }

    const int which = n0 / DOUT;
    if (which < 2) {
        // Q/K epilogue via LDS: scalar swizzled writes, then coalesced b128 stores.
        short* ldsT = lds;   // 64 x 128 shorts = 16 KB
        const float sc = (which == 0) ? QSCALE : 1.0f;
        short* dst = (which == 0) ? Qb : Kb;
        const int n0sec = n0 - which * DOUT;
        for (int mh = 0; mh < 2; mh++) {
            if ((w >> 1) == mh) {
                for (int i = 0; i < 4; i++)
                    for (int j = 0; j < 4; j++) {
                        int col = wn + j * 16 + l15;
                        int cx = col >> 3, co = col & 7;
                        for (int r = 0; r < 4; r++) {
                            int row = i * 16 + quad * 4 + r;
                            ldsT[row * 128 + ((cx ^ (row & 7)) * 8 + co)] = f2bf(acc[i][j][r] * sc);
                        }
                    }
            }
            __syncthreads();
            for (int p = 0; p < 4; p++) {
                int row = p * 16 + (t >> 4);
                int cL = t & 15;
                short8v v = *(const short8v*)&ldsT[row * 128 + ((cL ^ (row & 7)) * 8)];
                int mg = m0 + mh * 64 + row;
                int b2 = mg >> 11, tq = mg & 2047;
                int colg = n0sec + cL * 8;
                int hh = colg >> 6, d = colg & 63;
                *(short8v*)&dst[((size_t)((b2 * HH + hh) * TT + tq) << 6) + d] = v;
            }
            __syncthreads();
        }
    } else {
        // V: transpose tile in LDS (swizzled), coalesced b128 stores to Vt[b,h,d,t]
        short* ldsT = lds;   // 128 x 64 shorts = 16 KB
        const int n0r = n0 - 2 * DOUT;
        const int b = m0 >> 11, tq0 = m0 & 2047;
        for (int mh = 0; mh < 2; mh++) {
            if ((w >> 1) == mh) {
                for (int i = 0; i < 4; i++)
                    for (int j = 0; j < 4; j++)
                        for (int r = 0; r < 4; r++) {
                            int nl = wn + j * 16 + l15;
                            int ml = i * 16 + quad * 4 + r;
                            int c = ml >> 3, o = ml & 7;
                            ldsT[nl * 64 + ((c ^ (nl & 7)) * 8 + o)] = f2bf(acc[i][j][r]);
                        }
            }
            __syncthreads();
            for (int pass = 0; pass < 4; pass++) {
                int nrow = pass * 32 + (t >> 3);
                int cc = t & 7;
                short8v v = *(const short8v*)&ldsT[nrow * 64 + ((cc ^ (nrow & 7)) * 8)];
                int colg = n0r + nrow;
                int hh = colg >> 6, d = colg & 63;
                *(short8v*)&Vt[(size_t)((b * HH + hh) * HD + d) * TT + tq0 + mh * 64 + cc * 8] = v;
            }
            __syncthreads();
        }
    }
}

// ---- Flash attention R4: 32x32x16 MFMA, K-row-permuted staging, no P LDS ----
// grid (48 bh, 16 q-blocks of 128); block = 2 waves; wave = 64 q rows (2x32 tiles)
__global__ __launch_bounds__(128, 2) void attn_kernel(const short* __restrict__ Qb,
                                                      const short* __restrict__ Kb,
                                                      const short* __restrict__ Vt,
                                                      short* __restrict__ Ctx) {
    __shared__ __align__(16) short ldsK[2][64 * 64];   // [kslot][d] swizzled+permuted
    __shared__ __align__(16) short ldsV[2][64 * 64];   // [d][t] swizzled
    const int t = threadIdx.x;
    const int w = t >> 6, lane = t & 63;
    const int half = lane >> 5, m = lane & 31;
    const int bh = blockIdx.x;
    const int b = bh / HH, h = bh - b * HH;
    const int q0 = blockIdx.y * 128 + w * 64;

    const short* Qbase = Qb + (size_t)bh * TT * HD;
    const short* Kbase = Kb + (size_t)bh * TT * HD;
    const short* Vbase = Vt + (size_t)bh * HD * TT;

    // Q^T B-frags: B[k=d][n=q]: lane holds Q[q=m][d = step*16 + half*8 + j]
    bf16x8 qf[2][4];
#pragma unroll
    for (int tile = 0; tile < 2; tile++)
#pragma unroll
        for (int s = 0; s < 4; s++)
            qf[tile][s] = *(const bf16x8*)&Qbase[(q0 + tile * 32 + m) * HD + s * 16 + half * 8];

    // staging offsets (shorts). K rows permuted: LDS slot r holds K row pi(r),
    // pi = bit-permute so S^T regs land exactly in PV A-frag order.
    int kOff[4], vOff[4], dOff[4];
#pragma unroll
    for (int g = 0; g < 4; g++) {
        int row = g * 16 + (t >> 3);
        int r5 = row & 31, kt = row >> 5;
        int pi = ((r5 >> 3) & 1) * 16 + ((r5 >> 2) & 1) * 8 + ((r5 >> 4) & 1) * 4 + (r5 & 3);
        kOff[g] = (kt * 32 + pi) * 64 + (((t & 7) ^ (row & 7)) * 8);
        vOff[g] = row * TT + (((t & 7) ^ (row & 7)) * 8);
        dOff[g] = (g * 128 + t) * 8;
    }

    auto stage = [&](int buf, int u0) {
#pragma unroll
        for (int g = 0; g < 4; g++)
            gload_lds16(Kbase + (size_t)u0 * 64 + kOff[g], &ldsK[buf][dOff[g]]);
#pragma unroll
        for (int g = 0; g < 4; g++)
            gload_lds16(Vbase + (size_t)u0 + vOff[g], &ldsV[buf][dOff[g]]);
    };

    float16v accO[2][2];
    accO[0][0] = (float16v)0.0f; accO[0][1] = (float16v)0.0f;
    accO[1][0] = (float16v)0.0f; accO[1][1] = (float16v)0.0f;
    float lsum[2] = {0.0f, 0.0f};

    stage(0, 0);

    for (int it = 0; it < TT / 64; ++it) {
        __syncthreads();
        const int buf = it & 1;
        if (it + 1 < TT / 64) stage(buf ^ 1, (it + 1) * 64);
        const short* K_ = &ldsK[buf][0];
        const short* V_ = &ldsV[buf][0];

#pragma unroll
        for (int kt = 0; kt < 2; kt++) {
            // S^T tiles (32 kcols x 32 q) for both q-tiles, sharing K A-frags
            float16v st[2];
            st[0] = (float16v)0.0f; st[1] = (float16v)0.0f;
#pragma unroll
            for (int s = 0; s < 4; s++) {
                bf16x8 ka = *(const bf16x8*)&K_[(kt * 32 + m) * 64 + (((s * 2 + half) ^ (m & 7)) * 8)];
                st[0] = __builtin_amdgcn_mfma_f32_32x32x16_bf16(ka, qf[0][s], st[0], 0, 0, 0);
                st[1] = __builtin_amdgcn_mfma_f32_32x32x16_bf16(ka, qf[1][s], st[1], 0, 0, 0);
            }
            // exp2 in regs; register re-labeling gives the two PV A-frags directly
            bf16x8 ap[2][2];
#pragma unroll
            for (int tile = 0; tile < 2; tile++) {
                float pe[16];
#pragma unroll
                for (int i = 0; i < 16; i++) pe[i] = __builtin_amdgcn_exp2f(st[tile][i]);
                float s01 = 0.0f;
#pragma unroll
                for (int i = 0; i < 16; i++) s01 += pe[i];
                lsum[tile] += s01;
#pragma unroll
                for (int i = 0; i < 4; i++) {
                    ap[tile][0][i]     = (__bf16)pe[i];        // regs 0-3   -> k 0-3 (+8h)
                    ap[tile][0][4 + i] = (__bf16)pe[8 + i];    // regs 8-11  -> k 4-7
                    ap[tile][1][i]     = (__bf16)pe[4 + i];    // regs 4-7   -> k 0-3, ks=1
                    ap[tile][1][4 + i] = (__bf16)pe[12 + i];   // regs 12-15 -> k 4-7
                }
            }
            // O += P V, sharing V B-frags across q-tiles
#pragma unroll
            for (int ks = 0; ks < 2; ks++)
#pragma unroll
                for (int dt = 0; dt < 2; dt++) {
                    int row = dt * 32 + m;
                    bf16x8 bv = *(const bf16x8*)&V_[row * 64 + (((kt * 4 + ks * 2 + half) ^ (row & 7)) * 8)];
                    accO[0][dt] = __builtin_amdgcn_mfma_f32_32x32x16_bf16(ap[0][ks], bv, accO[0][dt], 0, 0, 0);
                    accO[1][dt] = __builtin_amdgcn_mfma_f32_32x32x16_bf16(ap[1][ks], bv, accO[1][dt], 0, 0, 0);
                }
        }
    }

    // normalize + store: accO D-layout col = d = m, row q = i + 8s + 4*half
#pragma unroll
    for (int tile = 0; tile < 2; tile++) {
        float v = lsum[tile] + __shfl_xor(lsum[tile], 32);
        float linv = 1.0f / v;
#pragma unroll
        for (int s = 0; s < 4; s++)
#pragma unroll
            for (int i = 0; i < 4; i++) {
                int reg = s * 4 + i;
                int qrow = i + s * 8 + half * 4;
                float ln = __shfl(linv, qrow);
                int qg = q0 + tile * 32 + qrow;
                size_t base = (size_t)(b * TT + qg) * DOUT + h * HD + m;
                Ctx[base]      = f2bf(accO[tile][0][reg] * ln);
                Ctx[base + 32] = f2bf(accO[tile][1][reg] * ln);
            }
    }
}

// ---- Out GEMM: out[8192][768] = Ctx @ Wot^T + bo (fp32 out) ----
__global__ __launch_bounds__(256) void out_gemm_kernel(const short* __restrict__ Cb,
                                                       const short* __restrict__ Wot,
                                                       const float* __restrict__ bo,
                                                       float* __restrict__ out) {
    __shared__ __align__(16) short ldsA[128 * 32];
    __shared__ __align__(16) short ldsB[128 * 32];
    const int t = threadIdx.x;
    const int w = t >> 6, lane = t & 63;
    const int quad = lane >> 4, l15 = lane & 15;
    const int m0 = blockIdx.x * 128, n0 = blockIdx.y * 128;
    const int wm = (w >> 1) * 64, wn = (w & 1) * 64;

    float4v acc[4][4];
    for (int i = 0; i < 4; i++)
        for (int j = 0; j < 4; j++)
            acc[i][j] = (float4v)0.0f;

    const int rA = t >> 2;
    const int cSw = ((t & 3) ^ ((t >> 3) & 3)) * 8;
    const short* gA0 = Cb + (size_t)(m0 + rA) * DOUT + cSw;
    const short* gB0 = Wot + (size_t)(n0 + rA) * DOUT + cSw;
    const int pos = (quad ^ ((l15 >> 1) & 3)) * 8;

    for (int k0 = 0; k0 < DOUT; k0 += 32) {
        gload_lds16(gA0 + k0,             &ldsA[t * 8]);
        gload_lds16(gA0 + 64 * DOUT + k0, &ldsA[(t + 256) * 8]);
        gload_lds16(gB0 + k0,             &ldsB[t * 8]);
        gload_lds16(gB0 + 64 * DOUT + k0, &ldsB[(t + 256) * 8]);
        __syncthreads();
        bf16x8 af[4], bfr[4];
        for (int i = 0; i < 4; i++) af[i]  = *(const bf16x8*)&ldsA[(wm + i * 16 + l15) * 32 + pos];
        for (int j = 0; j < 4; j++) bfr[j] = *(const bf16x8*)&ldsB[(wn + j * 16 + l15) * 32 + pos];
        for (int i = 0; i < 4; i++)
            for (int j = 0; j < 4; j++)
                acc[i][j] = __builtin_amdgcn_mfma_f32_16x16x32_bf16(af[i], bfr[j], acc[i][j], 0, 0, 0);
        __syncthreads();
    }

    for (int i = 0; i < 4; i++) {
        int m = m0 + wm + i * 16 + quad * 4;
        for (int j = 0; j < 4; j++) {
            int n = n0 + wn + j * 16 + l15;
            float bias = bo[n];
            for (int r = 0; r < 4; r++)
                out[(size_t)(m + r) * DOUT + n] = acc[i][j][r] + bias;
        }
    }
}

extern "C" void kernel_launch(void* const* d_in, const int* in_sizes, int n_in,
                              void* d_out, int out_size, void* d_ws, size_t ws_size,
                              hipStream_t stream) {
    const float* x  = (const float*)d_in[0];
    const float* Wq = (const float*)d_in[1];
    const float* Wk = (const float*)d_in[2];
    const float* Wv = (const float*)d_in[3];
    const float* Wo = (const float*)d_in[4];
    const float* bo = (const float*)d_in[5];
    float* out = (float*)d_out;

    char* ws = (char*)d_ws;
    short* Xb    = (short*)(ws + 0);          // 12582912
    short* Wqkvt = (short*)(ws + 12582912);   //  3538944
    short* Wot   = (short*)(ws + 16121856);   //  1179648
    short* Qb    = (short*)(ws + 17301504);   // 12582912
    short* Kb    = (short*)(ws + 29884416);   // 12582912
    short* Vt    = (short*)(ws + 42467328);   // 12582912
    short* Cb    = (short*)(ws + 55050240);   // 12582912 -> total 67633152 B

    cast_x_kernel<<<(MTOT * DIN / 4 + 255) / 256, 256, 0, stream>>>(x, Xb, MTOT * DIN / 4);
    prep_w_kernel<<<dim3(24, 24, 4), 256, 0, stream>>>(Wq, Wk, Wv, Wo, Wqkvt, Wot);
    qkv_gemm_kernel<<<dim3(MTOT / 128, NQKV / 128), 256, 0, stream>>>(Xb, Wqkvt, Qb, Kb, Vt);
    attn_kernel<<<dim3(BB * HH, TT / 128), 128, 0, stream>>>(Qb, Kb, Vt, Cb);
    out_gemm_kernel<<<dim3(MTOT / 128, DOUT / 128), 256, 0, stream>>>(Cb, Wot, bo, out);
}

// Round 5
// 217.404 us; speedup vs baseline: 1.0230x; 1.0230x over previous
//
#include <hip/hip_runtime.h>
#include <hip/hip_bf16.h>
#include <stdint.h>

// MHA fwd, B=4 T=2048 D=768 H=12 HD=64, fp32 io, NO mask, scale=1/8.
// R5: attn re-partitioned for occupancy: 4 waves x 32 q-rows (256 thr), grid 768
// -> 12 waves/CU (was 6). Same 32x32x16 MFMA + K-row permutation (P in regs).

#define HH   12
#define TT   2048
#define DIN  768
#define DOUT 768
#define HD   64
#define BB   4
#define MTOT (BB*TT)      // 8192
#define NQKV (3*DOUT)     // 2304
#define QSCALE 0.1803368801111832f   // 0.125 * log2(e)

typedef float  float4v  __attribute__((ext_vector_type(4)));
typedef float  float16v __attribute__((ext_vector_type(16)));
typedef __bf16 bf16x8   __attribute__((ext_vector_type(8)));
typedef short  short8v  __attribute__((ext_vector_type(8)));

#define AS1 __attribute__((address_space(1)))
#define AS3 __attribute__((address_space(3)))

static __device__ __forceinline__ void gload_lds16(const void* g, void* l) {
    __builtin_amdgcn_global_load_lds((AS1 void*)g, (AS3 void*)l, 16, 0, 0);
}

static __device__ __forceinline__ short f2bf(float f) {
    __bf16 h = (__bf16)f;
    return __builtin_bit_cast(short, h);
}

__global__ __launch_bounds__(256) void cast_x_kernel(const float* __restrict__ x,
                                                     short* __restrict__ xb, int n4) {
    int i = blockIdx.x * 256 + threadIdx.x;
    if (i >= n4) return;
    float4 v = ((const float4*)x)[i];
    short4 o;
    o.x = f2bf(v.x); o.y = f2bf(v.y); o.z = f2bf(v.z); o.w = f2bf(v.w);
    ((short4*)xb)[i] = o;
}

// Tiled transpose: Wqkvt[n][k] = W*[k][n] (bf16), Wot[n][k] = Wo[k][n].
__global__ __launch_bounds__(256) void prep_w_kernel(const float* __restrict__ Wq,
                                                     const float* __restrict__ Wk,
                                                     const float* __restrict__ Wv,
                                                     const float* __restrict__ Wo,
                                                     short* __restrict__ Wqkvt,
                                                     short* __restrict__ Wot) {
    __shared__ short tile[32 * 33];
    const int bx = blockIdx.x, by = blockIdx.y, bz = blockIdx.z;
    const float* W = (bz == 0) ? Wq : (bz == 1) ? Wk : (bz == 2) ? Wv : Wo;
    const int tx = threadIdx.x & 31, ty = threadIdx.x >> 5;
    for (int i = 0; i < 4; i++) {
        int k = by * 32 + ty + i * 8;
        tile[(ty + i * 8) * 33 + tx] = f2bf(W[(size_t)k * DOUT + bx * 32 + tx]);
    }
    __syncthreads();
    for (int i = 0; i < 4; i++) {
        int n = bx * 32 + ty + i * 8;
        int k = by * 32 + tx;
        short v = tile[tx * 33 + ty + i * 8];
        if (bz < 3) Wqkvt[(size_t)(bz * DOUT + n) * DIN + k] = v;
        else        Wot[(size_t)n * DOUT + k] = v;
    }
}

// ---- QKV GEMM: C[8192][2304] = Xb @ Wqkvt^T ----
__global__ __launch_bounds__(256) void qkv_gemm_kernel(const short* __restrict__ Xb,
                                                       const short* __restrict__ Wt,
                                                       short* __restrict__ Qb,
                                                       short* __restrict__ Kb,
                                                       short* __restrict__ Vt) {
    __shared__ __align__(16) short lds[8192];    // ldsA | ldsB; reused as epilogue tile
    short* ldsA = lds;
    short* ldsB = lds + 4096;
    const int t = threadIdx.x;
    const int w = t >> 6, lane = t & 63;
    const int quad = lane >> 4, l15 = lane & 15;
    const int m0 = blockIdx.x * 128, n0 = blockIdx.y * 128;
    const int wm = (w >> 1) * 64, wn = (w & 1) * 64;

    float4v acc[4][4];
    for (int i = 0; i < 4; i++)
        for (int j = 0; j < 4; j++)
            acc[i][j] = (float4v)0.0f;

    const int rA = t >> 2;
    const int cSw = ((t & 3) ^ ((t >> 3) & 3)) * 8;
    const short* gA0 = Xb + (size_t)(m0 + rA) * DIN + cSw;
    const short* gB0 = Wt + (size_t)(n0 + rA) * DIN + cSw;
    const int pos = (quad ^ ((l15 >> 1) & 3)) * 8;

    for (int k0 = 0; k0 < DIN; k0 += 32) {
        gload_lds16(gA0 + k0,            &ldsA[t * 8]);
        gload_lds16(gA0 + 64 * DIN + k0, &ldsA[(t + 256) * 8]);
        gload_lds16(gB0 + k0,            &ldsB[t * 8]);
        gload_lds16(gB0 + 64 * DIN + k0, &ldsB[(t + 256) * 8]);
        __syncthreads();
        bf16x8 af[4], bfr[4];
        for (int i = 0; i < 4; i++) af[i]  = *(const bf16x8*)&ldsA[(wm + i * 16 + l15) * 32 + pos];
        for (int j = 0; j < 4; j++) bfr[j] = *(const bf16x8*)&ldsB[(wn + j * 16 + l15) * 32 + pos];
        for (int i = 0; i < 4; i++)
            for (int j = 0; j < 4; j++)
                acc[i][j] = __builtin_amdgcn_mfma_f32_16x16x32_bf16(af[i], bfr[j], acc[i][j], 0, 0, 0);
        __syncthreads();
    }

    const int which = n0 / DOUT;
    if (which < 2) {
        // Q/K epilogue via LDS: scalar swizzled writes, then coalesced b128 stores.
        short* ldsT = lds;   // 64 x 128 shorts = 16 KB
        const float sc = (which == 0) ? QSCALE : 1.0f;
        short* dst = (which == 0) ? Qb : Kb;
        const int n0sec = n0 - which * DOUT;
        for (int mh = 0; mh < 2; mh++) {
            if ((w >> 1) == mh) {
                for (int i = 0; i < 4; i++)
                    for (int j = 0; j < 4; j++) {
                        int col = wn + j * 16 + l15;
                        int cx = col >> 3, co = col & 7;
                        for (int r = 0; r < 4; r++) {
                            int row = i * 16 + quad * 4 + r;
                            ldsT[row * 128 + ((cx ^ (row & 7)) * 8 + co)] = f2bf(acc[i][j][r] * sc);
                        }
                    }
            }
            __syncthreads();
            for (int p = 0; p < 4; p++) {
                int row = p * 16 + (t >> 4);
                int cL = t & 15;
                short8v v = *(const short8v*)&ldsT[row * 128 + ((cL ^ (row & 7)) * 8)];
                int mg = m0 + mh * 64 + row;
                int b2 = mg >> 11, tq = mg & 2047;
                int colg = n0sec + cL * 8;
                int hh = colg >> 6, d = colg & 63;
                *(short8v*)&dst[((size_t)((b2 * HH + hh) * TT + tq) << 6) + d] = v;
            }
            __syncthreads();
        }
    } else {
        // V: transpose tile in LDS (swizzled), coalesced b128 stores to Vt[b,h,d,t]
        short* ldsT = lds;   // 128 x 64 shorts = 16 KB
        const int n0r = n0 - 2 * DOUT;
        const int b = m0 >> 11, tq0 = m0 & 2047;
        for (int mh = 0; mh < 2; mh++) {
            if ((w >> 1) == mh) {
                for (int i = 0; i < 4; i++)
                    for (int j = 0; j < 4; j++)
                        for (int r = 0; r < 4; r++) {
                            int nl = wn + j * 16 + l15;
                            int ml = i * 16 + quad * 4 + r;
                            int c = ml >> 3, o = ml & 7;
                            ldsT[nl * 64 + ((c ^ (nl & 7)) * 8 + o)] = f2bf(acc[i][j][r]);
                        }
            }
            __syncthreads();
            for (int pass = 0; pass < 4; pass++) {
                int nrow = pass * 32 + (t >> 3);
                int cc = t & 7;
                short8v v = *(const short8v*)&ldsT[nrow * 64 + ((cc ^ (nrow & 7)) * 8)];
                int colg = n0r + nrow;
                int hh = colg >> 6, d = colg & 63;
                *(short8v*)&Vt[(size_t)((b * HH + hh) * HD + d) * TT + tq0 + mh * 64 + cc * 8] = v;
            }
            __syncthreads();
        }
    }
}

// ---- Flash attention R5: 32x32x16 MFMA, K-row-permuted staging, P in regs ----
// grid (48 bh, 16 q-blocks of 128); block = 4 waves x 32 q rows -> 12 waves/CU
__global__ __launch_bounds__(256, 3) void attn_kernel(const short* __restrict__ Qb,
                                                      const short* __restrict__ Kb,
                                                      const short* __restrict__ Vt,
                                                      short* __restrict__ Ctx) {
    __shared__ __align__(16) short ldsK[2][64 * 64];   // [kslot][d] swizzled+permuted
    __shared__ __align__(16) short ldsV[2][64 * 64];   // [d][t] swizzled
    const int t = threadIdx.x;
    const int w = t >> 6, lane = t & 63;
    const int half = lane >> 5, m = lane & 31;
    const int bh = blockIdx.x;
    const int b = bh / HH, h = bh - b * HH;
    const int q0 = blockIdx.y * 128 + w * 32;

    const short* Qbase = Qb + (size_t)bh * TT * HD;
    const short* Kbase = Kb + (size_t)bh * TT * HD;
    const short* Vbase = Vt + (size_t)bh * HD * TT;

    // Q^T B-frag: lane holds Q[q=m][d = s*16 + half*8 + j]
    bf16x8 qf[4];
#pragma unroll
    for (int s = 0; s < 4; s++)
        qf[s] = *(const bf16x8*)&Qbase[(q0 + m) * HD + s * 16 + half * 8];

    // staging offsets (shorts). K rows permuted within each 32-group: slot r holds
    // K row pi(r) so S^T regs land exactly in PV A-frag order. 256 threads, 2 groups.
    int kOff[2], vOff[2];
    {
        int r5 = t >> 3;              // 0..31
        int pi = ((r5 >> 3) & 1) * 16 + ((r5 >> 2) & 1) * 8 + ((r5 >> 4) & 1) * 4 + (r5 & 3);
#pragma unroll
        for (int g = 0; g < 2; g++) {
            kOff[g] = (g * 32 + pi) * 64 + (((t & 7) ^ (r5 & 7)) * 8);
            int vrow = g * 32 + r5;
            vOff[g] = vrow * TT + (((t & 7) ^ (vrow & 7)) * 8);
        }
    }

    auto stage = [&](int buf, int u0) {
#pragma unroll
        for (int g = 0; g < 2; g++)
            gload_lds16(Kbase + (size_t)u0 * 64 + kOff[g] + (size_t)g * 32 * 64 - (size_t)g * 32 * 64,
                        &ldsK[buf][(g * 256 + t) * 8]);
#pragma unroll
        for (int g = 0; g < 2; g++)
            gload_lds16(Vbase + (size_t)u0 + vOff[g], &ldsV[buf][(g * 256 + t) * 8]);
    };

    float16v accO[2];
    accO[0] = (float16v)0.0f;
    accO[1] = (float16v)0.0f;
    float lsum = 0.0f;

    stage(0, 0);

    for (int it = 0; it < TT / 64; ++it) {
        __syncthreads();
        const int buf = it & 1;
        if (it + 1 < TT / 64) stage(buf ^ 1, (it + 1) * 64);
        const short* K_ = &ldsK[buf][0];
        const short* V_ = &ldsV[buf][0];

#pragma unroll
        for (int kt = 0; kt < 2; kt++) {
            // S^T tile (32 kcols x 32 q)
            float16v st = (float16v)0.0f;
#pragma unroll
            for (int s = 0; s < 4; s++) {
                bf16x8 ka = *(const bf16x8*)&K_[(kt * 32 + m) * 64 + (((s * 2 + half) ^ (m & 7)) * 8)];
                st = __builtin_amdgcn_mfma_f32_32x32x16_bf16(ka, qf[s], st, 0, 0, 0);
            }
            // exp2 in regs; re-labeling gives the two PV A-frags directly
            float pe[16];
#pragma unroll
            for (int i = 0; i < 16; i++) pe[i] = __builtin_amdgcn_exp2f(st[i]);
            float s01 = 0.0f;
#pragma unroll
            for (int i = 0; i < 16; i++) s01 += pe[i];
            lsum += s01;
            bf16x8 ap[2];
#pragma unroll
            for (int i = 0; i < 4; i++) {
                ap[0][i]     = (__bf16)pe[i];        // regs 0-3   -> k 0-3 (+8h)
                ap[0][4 + i] = (__bf16)pe[8 + i];    // regs 8-11  -> k 4-7
                ap[1][i]     = (__bf16)pe[4 + i];    // regs 4-7   -> k 0-3, ks=1
                ap[1][4 + i] = (__bf16)pe[12 + i];   // regs 12-15 -> k 4-7
            }
            // O += P V
#pragma unroll
            for (int ks = 0; ks < 2; ks++)
#pragma unroll
                for (int dt = 0; dt < 2; dt++) {
                    int row = dt * 32 + m;
                    bf16x8 bv = *(const bf16x8*)&V_[row * 64 + (((kt * 4 + ks * 2 + half) ^ (row & 7)) * 8)];
                    accO[dt] = __builtin_amdgcn_mfma_f32_32x32x16_bf16(ap[ks], bv, accO[dt], 0, 0, 0);
                }
        }
    }

    // normalize + store: accO D-layout col = d = m, row q = i + 8s + 4*half
    {
        float v = lsum + __shfl_xor(lsum, 32);
        float linv = 1.0f / v;
#pragma unroll
        for (int s = 0; s < 4; s++)
#pragma unroll
            for (int i = 0; i < 4; i++) {
                int reg = s * 4 + i;
                int qrow = i + s * 8 + half * 4;
                float ln = __shfl(linv, qrow);
                int qg = q0 + qrow;
                size_t base = (size_t)(b * TT + qg) * DOUT + h * HD + m;
                Ctx[base]      = f2bf(accO[0][reg] * ln);
                Ctx[base + 32] = f2bf(accO[1][reg] * ln);
            }
    }
}

// ---- Out GEMM: out[8192][768] = Ctx @ Wot^T + bo (fp32 out) ----
__global__ __launch_bounds__(256) void out_gemm_kernel(const short* __restrict__ Cb,
                                                       const short* __restrict__ Wot,
                                                       const float* __restrict__ bo,
                                                       float* __restrict__ out) {
    __shared__ __align__(16) short ldsA[128 * 32];
    __shared__ __align__(16) short ldsB[128 * 32];
    const int t = threadIdx.x;
    const int w = t >> 6, lane = t & 63;
    const int quad = lane >> 4, l15 = lane & 15;
    const int m0 = blockIdx.x * 128, n0 = blockIdx.y * 128;
    const int wm = (w >> 1) * 64, wn = (w & 1) * 64;

    float4v acc[4][4];
    for (int i = 0; i < 4; i++)
        for (int j = 0; j < 4; j++)
            acc[i][j] = (float4v)0.0f;

    const int rA = t >> 2;
    const int cSw = ((t & 3) ^ ((t >> 3) & 3)) * 8;
    const short* gA0 = Cb + (size_t)(m0 + rA) * DOUT + cSw;
    const short* gB0 = Wot + (size_t)(n0 + rA) * DOUT + cSw;
    const int pos = (quad ^ ((l15 >> 1) & 3)) * 8;

    for (int k0 = 0; k0 < DOUT; k0 += 32) {
        gload_lds16(gA0 + k0,             &ldsA[t * 8]);
        gload_lds16(gA0 + 64 * DOUT + k0, &ldsA[(t + 256) * 8]);
        gload_lds16(gB0 + k0,             &ldsB[t * 8]);
        gload_lds16(gB0 + 64 * DOUT + k0, &ldsB[(t + 256) * 8]);
        __syncthreads();
        bf16x8 af[4], bfr[4];
        for (int i = 0; i < 4; i++) af[i]  = *(const bf16x8*)&ldsA[(wm + i * 16 + l15) * 32 + pos];
        for (int j = 0; j < 4; j++) bfr[j] = *(const bf16x8*)&ldsB[(wn + j * 16 + l15) * 32 + pos];
        for (int i = 0; i < 4; i++)
            for (int j = 0; j < 4; j++)
                acc[i][j] = __builtin_amdgcn_mfma_f32_16x16x32_bf16(af[i], bfr[j], acc[i][j], 0, 0, 0);
        __syncthreads();
    }

    for (int i = 0; i < 4; i++) {
        int m = m0 + wm + i * 16 + quad * 4;
        for (int j = 0; j < 4; j++) {
            int n = n0 + wn + j * 16 + l15;
            float bias = bo[n];
            for (int r = 0; r < 4; r++)
                out[(size_t)(m + r) * DOUT + n] = acc[i][j][r] + bias;
        }
    }
}

extern "C" void kernel_launch(void* const* d_in, const int* in_sizes, int n_in,
                              void* d_out, int out_size, void* d_ws, size_t ws_size,
                              hipStream_t stream) {
    const float* x  = (const float*)d_in[0];
    const float* Wq = (const float*)d_in[1];
    const float* Wk = (const float*)d_in[2];
    const float* Wv = (const float*)d_in[3];
    const float* Wo = (const float*)d_in[4];
    const float* bo = (const float*)d_in[5];
    float* out = (float*)d_out;

    char* ws = (char*)d_ws;
    short* Xb    = (short*)(ws + 0);          // 12582912
    short* Wqkvt = (short*)(ws + 12582912);   //  3538944
    short* Wot   = (short*)(ws + 16121856);   //  1179648
    short* Qb    = (short*)(ws + 17301504);   // 12582912
    short* Kb    = (short*)(ws + 29884416);   // 12582912
    short* Vt    = (short*)(ws + 42467328);   // 12582912
    short* Cb    = (short*)(ws + 55050240);   // 12582912 -> total 67633152 B

    cast_x_kernel<<<(MTOT * DIN / 4 + 255) / 256, 256, 0, stream>>>(x, Xb, MTOT * DIN / 4);
    prep_w_kernel<<<dim3(24, 24, 4), 256, 0, stream>>>(Wq, Wk, Wv, Wo, Wqkvt, Wot);
    qkv_gemm_kernel<<<dim3(MTOT / 128, NQKV / 128), 256, 0, stream>>>(Xb, Wqkvt, Qb, Kb, Vt);
    attn_kernel<<<dim3(BB * HH, TT / 128), 256, 0, stream>>>(Qb, Kb, Vt, Cb);
    out_gemm_kernel<<<dim3(MTOT / 128, DOUT / 128), 256, 0, stream>>>(Cb, Wot, bo, out);
}

// Round 6
// 208.214 us; speedup vs baseline: 1.0682x; 1.0441x over previous
//
#include <hip/hip_runtime.h>
#include <hip/hip_bf16.h>
#include <stdint.h>

// MHA fwd, B=4 T=2048 D=768 H=12 HD=64, fp32 io, NO mask, scale=1/8.
// R6: out_gemm re-tiled 64x128 (grid 768 = 3 blocks/CU, was 384 = 1.5);
// qkv epilogues single-pass via 32KB LDS (1 barrier, was 4, no idle waves).
// attn frozen from R5 (65.7 us; floor analysis says ~42 us needs split-K).

#define HH   12
#define TT   2048
#define DIN  768
#define DOUT 768
#define HD   64
#define BB   4
#define MTOT (BB*TT)      // 8192
#define NQKV (3*DOUT)     // 2304
#define QSCALE 0.1803368801111832f   // 0.125 * log2(e)

typedef float  float4v  __attribute__((ext_vector_type(4)));
typedef float  float16v __attribute__((ext_vector_type(16)));
typedef __bf16 bf16x8   __attribute__((ext_vector_type(8)));
typedef short  short8v  __attribute__((ext_vector_type(8)));

#define AS1 __attribute__((address_space(1)))
#define AS3 __attribute__((address_space(3)))

static __device__ __forceinline__ void gload_lds16(const void* g, void* l) {
    __builtin_amdgcn_global_load_lds((AS1 void*)g, (AS3 void*)l, 16, 0, 0);
}

static __device__ __forceinline__ short f2bf(float f) {
    __bf16 h = (__bf16)f;
    return __builtin_bit_cast(short, h);
}

__global__ __launch_bounds__(256) void cast_x_kernel(const float* __restrict__ x,
                                                     short* __restrict__ xb, int n4) {
    int i = blockIdx.x * 256 + threadIdx.x;
    if (i >= n4) return;
    float4 v = ((const float4*)x)[i];
    short4 o;
    o.x = f2bf(v.x); o.y = f2bf(v.y); o.z = f2bf(v.z); o.w = f2bf(v.w);
    ((short4*)xb)[i] = o;
}

// Tiled transpose: Wqkvt[n][k] = W*[k][n] (bf16), Wot[n][k] = Wo[k][n].
__global__ __launch_bounds__(256) void prep_w_kernel(const float* __restrict__ Wq,
                                                     const float* __restrict__ Wk,
                                                     const float* __restrict__ Wv,
                                                     const float* __restrict__ Wo,
                                                     short* __restrict__ Wqkvt,
                                                     short* __restrict__ Wot) {
    __shared__ short tile[32 * 33];
    const int bx = blockIdx.x, by = blockIdx.y, bz = blockIdx.z;
    const float* W = (bz == 0) ? Wq : (bz == 1) ? Wk : (bz == 2) ? Wv : Wo;
    const int tx = threadIdx.x & 31, ty = threadIdx.x >> 5;
    for (int i = 0; i < 4; i++) {
        int k = by * 32 + ty + i * 8;
        tile[(ty + i * 8) * 33 + tx] = f2bf(W[(size_t)k * DOUT + bx * 32 + tx]);
    }
    __syncthreads();
    for (int i = 0; i < 4; i++) {
        int n = bx * 32 + ty + i * 8;
        int k = by * 32 + tx;
        short v = tile[tx * 33 + ty + i * 8];
        if (bz < 3) Wqkvt[(size_t)(bz * DOUT + n) * DIN + k] = v;
        else        Wot[(size_t)n * DOUT + k] = v;
    }
}

// ---- QKV GEMM: C[8192][2304] = Xb @ Wqkvt^T ----
__global__ __launch_bounds__(256) void qkv_gemm_kernel(const short* __restrict__ Xb,
                                                       const short* __restrict__ Wt,
                                                       short* __restrict__ Qb,
                                                       short* __restrict__ Kb,
                                                       short* __restrict__ Vt) {
    __shared__ __align__(16) short lds[16384];   // GEMM: A|B 16KB; epilogue: 32KB tile
    short* ldsA = lds;
    short* ldsB = lds + 4096;
    const int t = threadIdx.x;
    const int w = t >> 6, lane = t & 63;
    const int quad = lane >> 4, l15 = lane & 15;
    const int m0 = blockIdx.x * 128, n0 = blockIdx.y * 128;
    const int wm = (w >> 1) * 64, wn = (w & 1) * 64;

    float4v acc[4][4];
    for (int i = 0; i < 4; i++)
        for (int j = 0; j < 4; j++)
            acc[i][j] = (float4v)0.0f;

    const int rA = t >> 2;
    const int cSw = ((t & 3) ^ ((t >> 3) & 3)) * 8;
    const short* gA0 = Xb + (size_t)(m0 + rA) * DIN + cSw;
    const short* gB0 = Wt + (size_t)(n0 + rA) * DIN + cSw;
    const int pos = (quad ^ ((l15 >> 1) & 3)) * 8;

    for (int k0 = 0; k0 < DIN; k0 += 32) {
        gload_lds16(gA0 + k0,            &ldsA[t * 8]);
        gload_lds16(gA0 + 64 * DIN + k0, &ldsA[(t + 256) * 8]);
        gload_lds16(gB0 + k0,            &ldsB[t * 8]);
        gload_lds16(gB0 + 64 * DIN + k0, &ldsB[(t + 256) * 8]);
        __syncthreads();
        bf16x8 af[4], bfr[4];
        for (int i = 0; i < 4; i++) af[i]  = *(const bf16x8*)&ldsA[(wm + i * 16 + l15) * 32 + pos];
        for (int j = 0; j < 4; j++) bfr[j] = *(const bf16x8*)&ldsB[(wn + j * 16 + l15) * 32 + pos];
        for (int i = 0; i < 4; i++)
            for (int j = 0; j < 4; j++)
                acc[i][j] = __builtin_amdgcn_mfma_f32_16x16x32_bf16(af[i], bfr[j], acc[i][j], 0, 0, 0);
        __syncthreads();
    }

    const int which = n0 / DOUT;
    if (which < 2) {
        // Q/K epilogue: single-pass 128x128 LDS tile, 1 barrier, b128 stores.
        short* ldsT = lds;   // 128 x 128 shorts = 32 KB
        const float sc = (which == 0) ? QSCALE : 1.0f;
        short* dst = (which == 0) ? Qb : Kb;
        const int n0sec = n0 - which * DOUT;
        for (int i = 0; i < 4; i++)
            for (int j = 0; j < 4; j++) {
                int col = wn + j * 16 + l15;
                int cx = col >> 3, co = col & 7;
                for (int r = 0; r < 4; r++) {
                    int row = wm + i * 16 + quad * 4 + r;
                    ldsT[row * 128 + ((cx ^ (row & 7)) * 8 + co)] = f2bf(acc[i][j][r] * sc);
                }
            }
        __syncthreads();
        for (int p = 0; p < 8; p++) {
            int row = p * 16 + (t >> 4);
            int cL = t & 15;
            short8v v = *(const short8v*)&ldsT[row * 128 + ((cL ^ (row & 7)) * 8)];
            int mg = m0 + row;
            int b2 = mg >> 11, tq = mg & 2047;
            int colg = n0sec + cL * 8;
            int hh = colg >> 6, d = colg & 63;
            *(short8v*)&dst[((size_t)((b2 * HH + hh) * TT + tq) << 6) + d] = v;
        }
    } else {
        // V epilogue: single-pass transpose 128(d) x 128(t) LDS tile, b128 stores.
        short* ldsT = lds;   // 128 x 128 shorts = 32 KB
        const int n0r = n0 - 2 * DOUT;
        const int b = m0 >> 11, tq0 = m0 & 2047;
        for (int i = 0; i < 4; i++)
            for (int j = 0; j < 4; j++)
                for (int r = 0; r < 4; r++) {
                    int nl = wn + j * 16 + l15;            // d-direction 0..127
                    int ml = wm + i * 16 + quad * 4 + r;   // t-direction 0..127
                    int c = ml >> 3, o = ml & 7;
                    ldsT[nl * 128 + ((c ^ (nl & 7)) * 8 + o)] = f2bf(acc[i][j][r]);
                }
        __syncthreads();
        for (int p = 0; p < 8; p++) {
            int nrow = p * 16 + (t >> 4);
            int cc = t & 15;
            short8v v = *(const short8v*)&ldsT[nrow * 128 + ((cc ^ (nrow & 7)) * 8)];
            int colg = n0r + nrow;
            int hh = colg >> 6, d = colg & 63;
            *(short8v*)&Vt[(size_t)((b * HH + hh) * HD + d) * TT + tq0 + cc * 8] = v;
        }
    }
}

// ---- Flash attention (frozen from R5): 32x32x16, K-row-permuted, P in regs ----
__global__ __launch_bounds__(256, 3) void attn_kernel(const short* __restrict__ Qb,
                                                      const short* __restrict__ Kb,
                                                      const short* __restrict__ Vt,
                                                      short* __restrict__ Ctx) {
    __shared__ __align__(16) short ldsK[2][64 * 64];
    __shared__ __align__(16) short ldsV[2][64 * 64];
    const int t = threadIdx.x;
    const int w = t >> 6, lane = t & 63;
    const int half = lane >> 5, m = lane & 31;
    const int bh = blockIdx.x;
    const int b = bh / HH, h = bh - b * HH;
    const int q0 = blockIdx.y * 128 + w * 32;

    const short* Qbase = Qb + (size_t)bh * TT * HD;
    const short* Kbase = Kb + (size_t)bh * TT * HD;
    const short* Vbase = Vt + (size_t)bh * HD * TT;

    bf16x8 qf[4];
#pragma unroll
    for (int s = 0; s < 4; s++)
        qf[s] = *(const bf16x8*)&Qbase[(q0 + m) * HD + s * 16 + half * 8];

    int kOff[2], vOff[2];
    {
        int r5 = t >> 3;
        int pi = ((r5 >> 3) & 1) * 16 + ((r5 >> 2) & 1) * 8 + ((r5 >> 4) & 1) * 4 + (r5 & 3);
#pragma unroll
        for (int g = 0; g < 2; g++) {
            kOff[g] = (g * 32 + pi) * 64 + (((t & 7) ^ (r5 & 7)) * 8);
            int vrow = g * 32 + r5;
            vOff[g] = vrow * TT + (((t & 7) ^ (vrow & 7)) * 8);
        }
    }

    auto stage = [&](int buf, int u0) {
#pragma unroll
        for (int g = 0; g < 2; g++)
            gload_lds16(Kbase + (size_t)u0 * 64 + kOff[g], &ldsK[buf][(g * 256 + t) * 8]);
#pragma unroll
        for (int g = 0; g < 2; g++)
            gload_lds16(Vbase + (size_t)u0 + vOff[g], &ldsV[buf][(g * 256 + t) * 8]);
    };

    float16v accO[2];
    accO[0] = (float16v)0.0f;
    accO[1] = (float16v)0.0f;
    float lsum = 0.0f;

    stage(0, 0);

    for (int it = 0; it < TT / 64; ++it) {
        __syncthreads();
        const int buf = it & 1;
        if (it + 1 < TT / 64) stage(buf ^ 1, (it + 1) * 64);
        const short* K_ = &ldsK[buf][0];
        const short* V_ = &ldsV[buf][0];

#pragma unroll
        for (int kt = 0; kt < 2; kt++) {
            float16v st = (float16v)0.0f;
#pragma unroll
            for (int s = 0; s < 4; s++) {
                bf16x8 ka = *(const bf16x8*)&K_[(kt * 32 + m) * 64 + (((s * 2 + half) ^ (m & 7)) * 8)];
                st = __builtin_amdgcn_mfma_f32_32x32x16_bf16(ka, qf[s], st, 0, 0, 0);
            }
            float pe[16];
#pragma unroll
            for (int i = 0; i < 16; i++) pe[i] = __builtin_amdgcn_exp2f(st[i]);
            float s01 = 0.0f;
#pragma unroll
            for (int i = 0; i < 16; i++) s01 += pe[i];
            lsum += s01;
            bf16x8 ap[2];
#pragma unroll
            for (int i = 0; i < 4; i++) {
                ap[0][i]     = (__bf16)pe[i];
                ap[0][4 + i] = (__bf16)pe[8 + i];
                ap[1][i]     = (__bf16)pe[4 + i];
                ap[1][4 + i] = (__bf16)pe[12 + i];
            }
#pragma unroll
            for (int ks = 0; ks < 2; ks++)
#pragma unroll
                for (int dt = 0; dt < 2; dt++) {
                    int row = dt * 32 + m;
                    bf16x8 bv = *(const bf16x8*)&V_[row * 64 + (((kt * 4 + ks * 2 + half) ^ (row & 7)) * 8)];
                    accO[dt] = __builtin_amdgcn_mfma_f32_32x32x16_bf16(ap[ks], bv, accO[dt], 0, 0, 0);
                }
        }
    }

    {
        float v = lsum + __shfl_xor(lsum, 32);
        float linv = 1.0f / v;
#pragma unroll
        for (int s = 0; s < 4; s++)
#pragma unroll
            for (int i = 0; i < 4; i++) {
                int reg = s * 4 + i;
                int qrow = i + s * 8 + half * 4;
                float ln = __shfl(linv, qrow);
                int qg = q0 + qrow;
                size_t base = (size_t)(b * TT + qg) * DOUT + h * HD + m;
                Ctx[base]      = f2bf(accO[0][reg] * ln);
                Ctx[base + 32] = f2bf(accO[1][reg] * ln);
            }
    }
}

// ---- Out GEMM R6: 64x128 tiles, grid 128x6 = 768 blocks = 3/CU even ----
__global__ __launch_bounds__(256) void out_gemm_kernel(const short* __restrict__ Cb,
                                                       const short* __restrict__ Wot,
                                                       const float* __restrict__ bo,
                                                       float* __restrict__ out) {
    __shared__ __align__(16) short ldsA[64 * 32];    // 4 KB
    __shared__ __align__(16) short ldsB[128 * 32];   // 8 KB
    const int t = threadIdx.x;
    const int w = t >> 6, lane = t & 63;
    const int quad = lane >> 4, l15 = lane & 15;
    const int m0 = blockIdx.x * 64, n0 = blockIdx.y * 128;
    const int wn = w * 32;

    float4v acc[4][2];
    for (int i = 0; i < 4; i++)
        for (int j = 0; j < 2; j++)
            acc[i][j] = (float4v)0.0f;

    const int rA = t >> 2;
    const int cSw = ((t & 3) ^ ((t >> 3) & 3)) * 8;
    const short* gA0 = Cb + (size_t)(m0 + rA) * DOUT + cSw;
    const short* gB0 = Wot + (size_t)(n0 + rA) * DOUT + cSw;
    const int pos = (quad ^ ((l15 >> 1) & 3)) * 8;

    for (int k0 = 0; k0 < DOUT; k0 += 32) {
        gload_lds16(gA0 + k0,             &ldsA[t * 8]);
        gload_lds16(gB0 + k0,             &ldsB[t * 8]);
        gload_lds16(gB0 + 64 * DOUT + k0, &ldsB[(t + 256) * 8]);
        __syncthreads();
        bf16x8 af[4], bfr[2];
        for (int i = 0; i < 4; i++) af[i]  = *(const bf16x8*)&ldsA[(i * 16 + l15) * 32 + pos];
        for (int j = 0; j < 2; j++) bfr[j] = *(const bf16x8*)&ldsB[(wn + j * 16 + l15) * 32 + pos];
        for (int i = 0; i < 4; i++)
            for (int j = 0; j < 2; j++)
                acc[i][j] = __builtin_amdgcn_mfma_f32_16x16x32_bf16(af[i], bfr[j], acc[i][j], 0, 0, 0);
        __syncthreads();
    }

    for (int i = 0; i < 4; i++) {
        int m = m0 + i * 16 + quad * 4;
        for (int j = 0; j < 2; j++) {
            int n = n0 + wn + j * 16 + l15;
            float bias = bo[n];
            for (int r = 0; r < 4; r++)
                out[(size_t)(m + r) * DOUT + n] = acc[i][j][r] + bias;
        }
    }
}

extern "C" void kernel_launch(void* const* d_in, const int* in_sizes, int n_in,
                              void* d_out, int out_size, void* d_ws, size_t ws_size,
                              hipStream_t stream) {
    const float* x  = (const float*)d_in[0];
    const float* Wq = (const float*)d_in[1];
    const float* Wk = (const float*)d_in[2];
    const float* Wv = (const float*)d_in[3];
    const float* Wo = (const float*)d_in[4];
    const float* bo = (const float*)d_in[5];
    float* out = (float*)d_out;

    char* ws = (char*)d_ws;
    short* Xb    = (short*)(ws + 0);          // 12582912
    short* Wqkvt = (short*)(ws + 12582912);   //  3538944
    short* Wot   = (short*)(ws + 16121856);   //  1179648
    short* Qb    = (short*)(ws + 17301504);   // 12582912
    short* Kb    = (short*)(ws + 29884416);   // 12582912
    short* Vt    = (short*)(ws + 42467328);   // 12582912
    short* Cb    = (short*)(ws + 55050240);   // 12582912 -> total 67633152 B

    cast_x_kernel<<<(MTOT * DIN / 4 + 255) / 256, 256, 0, stream>>>(x, Xb, MTOT * DIN / 4);
    prep_w_kernel<<<dim3(24, 24, 4), 256, 0, stream>>>(Wq, Wk, Wv, Wo, Wqkvt, Wot);
    qkv_gemm_kernel<<<dim3(MTOT / 128, NQKV / 128), 256, 0, stream>>>(Xb, Wqkvt, Qb, Kb, Vt);
    attn_kernel<<<dim3(BB * HH, TT / 128), 256, 0, stream>>>(Qb, Kb, Vt, Cb);
    out_gemm_kernel<<<dim3(MTOT / 64, DOUT / 128), 256, 0, stream>>>(Cb, Wot, bo, out);
}